// Round 3
// baseline (17729.169 us; speedup 1.0000x reference)
//
#include <hip/hip_runtime.h>
#include <hip/hip_bf16.h>

#define N_PTS 20000
#define M_PTS 5000
#define NSAMP 16
#define CIN 64
#define COUT 128
#define FDIM 67          // 3 + CIN
#define NPT 20           // ceil(20000/1024) points per thread in FPS

typedef unsigned long long u64;

// monotone float->uint mapping (handles negative d from cancellation in knn)
__device__ __forceinline__ unsigned f2ord(float f) {
    unsigned u = __float_as_uint(f);
    return u ^ (((unsigned)((int)u >> 31)) | 0x80000000u);
}

// ---------------------------------------------------------------------------
// K1: furthest point sampling. Single block, 1024 threads, one CU.
// dist/coords in registers (20 pts/thread). Exact fp32 arithmetic, rn ops,
// tie -> lowest index (matches np.argmax first-occurrence).
// ---------------------------------------------------------------------------
__global__ __launch_bounds__(1024) void fps_kernel(
    const float* __restrict__ p,
    float* __restrict__ qxyz,          // [M*3] fp32 sampled coords (ws)
    float* __restrict__ stats,         // zero first 256 floats (BN accumulators)
    float* __restrict__ out)           // f32 output buffer
{
    const int t = threadIdx.x;
    __shared__ float bc[3];
    __shared__ u64 wred[16];

    if (t < 256) stats[t] = 0.0f;

    float px[NPT], py[NPT], pz[NPT], dist[NPT];
#pragma unroll
    for (int i = 0; i < NPT; ++i) {
        int idx = t + i * 1024;
        if (idx < N_PTS) {
            px[i] = p[3 * idx + 0];
            py[i] = p[3 * idx + 1];
            pz[i] = p[3 * idx + 2];
            dist[i] = 1e10f;
        } else {
            px[i] = py[i] = pz[i] = 0.0f;
            dist[i] = -1.0f;           // never selected
        }
    }

    if (t == 0) {
        bc[0] = px[0]; bc[1] = py[0]; bc[2] = pz[0];
        qxyz[0] = px[0]; qxyz[1] = py[0]; qxyz[2] = pz[0];
        out[0] = px[0]; out[1] = py[0]; out[2] = pz[0];
        out[M_PTS * 3 + M_PTS * COUT] = (float)M_PTS;   // n_o = 5000
    }
    __syncthreads();

    for (int it = 1; it < M_PTS; ++it) {
        const float lx = bc[0], ly = bc[1], lz = bc[2];
        float lm = -1.0f;
        int li = 0;
#pragma unroll
        for (int i = 0; i < NPT; ++i) {
            float dx = px[i] - lx, dy = py[i] - ly, dz = pz[i] - lz;
            float d = __fadd_rn(__fadd_rn(__fmul_rn(dx, dx), __fmul_rn(dy, dy)),
                                __fmul_rn(dz, dz));
            float nd = fminf(dist[i], d);
            dist[i] = nd;
            if (nd > lm) { lm = nd; li = t + i * 1024; }   // i asc => idx asc, '>' keeps lowest
        }
        unsigned vb = (lm >= 0.0f) ? __float_as_uint(lm) : 0u;  // dists >= 0: raw bits monotone
        u64 key = ((u64)vb << 32) | (unsigned)(~li);            // tie -> lower idx wins max
#pragma unroll
        for (int off = 32; off; off >>= 1) {
            u64 o = __shfl_xor(key, off, 64);
            key = (o > key) ? o : key;
        }
        if ((t & 63) == 0) wred[t >> 6] = key;
        __syncthreads();

        u64 k2 = wred[t & 15];
#pragma unroll
        for (int off = 8; off; off >>= 1) {
            u64 o = __shfl_xor(k2, off, 64);
            k2 = (o > k2) ? o : k2;
        }
        unsigned win_idx = ~((unsigned)(k2 & 0xFFFFFFFFu));

        if ((win_idx & 1023u) == (unsigned)t) {            // owner publishes coords
            int slot = win_idx >> 10;
            float wx = 0.f, wy = 0.f, wz = 0.f;
#pragma unroll
            for (int i = 0; i < NPT; ++i)
                if (i == slot) { wx = px[i]; wy = py[i]; wz = pz[i]; }
            bc[0] = wx; bc[1] = wy; bc[2] = wz;
            qxyz[3 * it + 0] = wx; qxyz[3 * it + 1] = wy; qxyz[3 * it + 2] = wz;
            out[3 * it + 0] = wx; out[3 * it + 1] = wy; out[3 * it + 2] = wz;
        }
        __syncthreads();
    }
}

// ---------------------------------------------------------------------------
// K2: kNN (k=16) per query. One block (256 threads) per query.
// Expanded-form distance matching the reference bitwise; packed (d,idx) keys.
// ---------------------------------------------------------------------------
__global__ __launch_bounds__(256) void knn_kernel(
    const float* __restrict__ p,
    const float* __restrict__ qxyz,
    int* __restrict__ nidx)
{
    const int m = blockIdx.x;
    const int t = threadIdx.x;
    __shared__ u64 red[4];

    const float qx = qxyz[3 * m], qy = qxyz[3 * m + 1], qz = qxyz[3 * m + 2];
    const float qq = __fadd_rn(__fadd_rn(__fmul_rn(qx, qx), __fmul_rn(qy, qy)),
                               __fmul_rn(qz, qz));

    u64 kv[NSAMP];
#pragma unroll
    for (int j = 0; j < NSAMP; ++j) kv[j] = ~0ULL;
    u64 curmax = ~0ULL;
    int cslot = 0;

#pragma unroll 2
    for (int i = 0; i < 79; ++i) {
        int n = t + i * 256;
        if (n < N_PTS) {
            float px = p[3 * n], py = p[3 * n + 1], pz = p[3 * n + 2];
            float pp = __fadd_rn(__fadd_rn(__fmul_rn(px, px), __fmul_rn(py, py)),
                                 __fmul_rn(pz, pz));
            float qp = __fadd_rn(__fadd_rn(__fmul_rn(qx, px), __fmul_rn(qy, py)),
                                 __fmul_rn(qz, pz));
            float d = __fadd_rn(__fsub_rn(qq, __fmul_rn(2.0f, qp)), pp);
            u64 key = ((u64)f2ord(d) << 32) | (unsigned)n;
            if (key < curmax) {
#pragma unroll
                for (int j = 0; j < NSAMP; ++j) if (j == cslot) kv[j] = key;
                curmax = 0;
#pragma unroll
                for (int j = 0; j < NSAMP; ++j)
                    if (kv[j] > curmax) { curmax = kv[j]; cslot = j; }
            }
        }
    }

    // merge 256x16 -> global top-16 (16 rounds of block argmin; keys unique)
    for (int r = 0; r < NSAMP; ++r) {
        u64 my = kv[0];
#pragma unroll
        for (int j = 1; j < NSAMP; ++j) my = (kv[j] < my) ? kv[j] : my;
        u64 k = my;
#pragma unroll
        for (int off = 32; off; off >>= 1) {
            u64 o = __shfl_xor(k, off, 64);
            k = (o < k) ? o : k;
        }
        if ((t & 63) == 0) red[t >> 6] = k;
        __syncthreads();
        u64 win = red[0];
        win = (red[1] < win) ? red[1] : win;
        win = (red[2] < win) ? red[2] : win;
        win = (red[3] < win) ? red[3] : win;
        if (my == win) {
#pragma unroll
            for (int j = 0; j < NSAMP; ++j) if (kv[j] == win) kv[j] = ~0ULL;
        }
        if (t == 0) nidx[m * NSAMP + r] = (int)(unsigned)(win & 0xFFFFFFFFu);
        __syncthreads();
    }
}

// ---------------------------------------------------------------------------
// K3: BN batch statistics. Row (m,j) -> feat[67] -> h[c]; accumulate sum/sumsq.
// ---------------------------------------------------------------------------
__global__ __launch_bounds__(128) void stats_kernel(
    const float* __restrict__ p,
    const float* __restrict__ x,
    const float* __restrict__ qxyz,
    const int* __restrict__ nidx,
    const float* __restrict__ W,
    float* __restrict__ stats)
{
    __shared__ float Wl[FDIM][COUT];
    __shared__ float feat[FDIM];
    const int t = threadIdx.x;

    for (int k = 0; k < FDIM; ++k) Wl[k][t] = W[k * COUT + t];

    float s = 0.0f, sq = 0.0f;
    for (int r = blockIdx.x; r < M_PTS * NSAMP; r += gridDim.x) {
        int m = r >> 4, j = r & 15;
        int n = nidx[m * NSAMP + j];
        n = max(0, min(n, N_PTS - 1));       // fault guard (no-op when nidx valid)
        __syncthreads();
        if (t < 3)         feat[t] = p[3 * n + t] - qxyz[3 * m + t];
        else if (t < FDIM) feat[t] = x[n * CIN + (t - 3)];
        __syncthreads();
        float h = 0.0f;
#pragma unroll
        for (int k = 0; k < FDIM; ++k) h = fmaf(feat[k], Wl[k][t], h);
        s += h;
        sq = fmaf(h, h, sq);
    }
    atomicAdd(&stats[t], s);
    atomicAdd(&stats[128 + t], sq);
}

// ---------------------------------------------------------------------------
// K4: finalize BN -> scale/shift (+ redundant n_o write)
// ---------------------------------------------------------------------------
__global__ __launch_bounds__(128) void finalize_kernel(
    const float* __restrict__ gamma,
    const float* __restrict__ beta,
    float* __restrict__ stats,
    float* __restrict__ out)
{
    const int t = threadIdx.x;
    const float inv = 1.0f / (float)(M_PTS * NSAMP);
    float mean = stats[t] * inv;
    float var = stats[128 + t] * inv - mean * mean;
    var = fmaxf(var, 0.0f);
    float sc = gamma[t] * rsqrtf(var + 1e-5f);
    stats[256 + t] = sc;
    stats[384 + t] = beta[t] - mean * sc;
    if (t == 0) out[M_PTS * 3 + M_PTS * COUT] = (float)M_PTS;  // n_o (redundant)
}

// ---------------------------------------------------------------------------
// K5: recompute h, affine + ReLU + max over k, write x_out (f32)
// ---------------------------------------------------------------------------
__global__ __launch_bounds__(128) void out_kernel(
    const float* __restrict__ p,
    const float* __restrict__ x,
    const float* __restrict__ qxyz,
    const int* __restrict__ nidx,
    const float* __restrict__ W,
    const float* __restrict__ stats,
    float* __restrict__ out)
{
    __shared__ float Wl[FDIM][COUT];
    __shared__ float feat[NSAMP][FDIM];
    const int m = blockIdx.x;
    const int t = threadIdx.x;

    for (int k = 0; k < FDIM; ++k) Wl[k][t] = W[k * COUT + t];

    for (int e = t; e < NSAMP * FDIM; e += 128) {
        int j = e / FDIM, k = e - j * FDIM;
        int n = nidx[m * NSAMP + j];
        n = max(0, min(n, N_PTS - 1));       // fault guard
        feat[j][k] = (k < 3) ? (p[3 * n + k] - qxyz[3 * m + k])
                             : x[n * CIN + (k - 3)];
    }
    __syncthreads();

    const float sc = stats[256 + t], sh = stats[384 + t];
    float mx = 0.0f;                       // relu(h) >= 0, so max >= 0
#pragma unroll
    for (int j = 0; j < NSAMP; ++j) {
        float h = 0.0f;
#pragma unroll
        for (int k = 0; k < FDIM; ++k) h = fmaf(feat[j][k], Wl[k][t], h);
        float y = fmaf(h, sc, sh);
        mx = fmaxf(mx, y);
    }
    out[M_PTS * 3 + m * COUT + t] = mx;
}

// ---------------------------------------------------------------------------
extern "C" void kernel_launch(void* const* d_in, const int* in_sizes, int n_in,
                              void* d_out, int out_size, void* d_ws, size_t ws_size,
                              hipStream_t stream)
{
    (void)in_sizes; (void)n_in; (void)out_size; (void)ws_size;
    const float* p     = (const float*)d_in[0];
    const float* x     = (const float*)d_in[1];
    const float* W     = (const float*)d_in[3];
    const float* gamma = (const float*)d_in[4];
    const float* beta  = (const float*)d_in[5];
    float* out = (float*)d_out;          // reference outputs are float32

    float* qxyz  = (float*)d_ws;                       // 15000 f32
    int*   nidx  = (int*)((char*)d_ws + 60000);        // 80000 i32
    float* stats = (float*)((char*)d_ws + 380000);     // 512 f32

    hipLaunchKernelGGL(fps_kernel,      dim3(1),     dim3(1024), 0, stream, p, qxyz, stats, out);
    hipLaunchKernelGGL(knn_kernel,      dim3(M_PTS), dim3(256),  0, stream, p, qxyz, nidx);
    hipLaunchKernelGGL(stats_kernel,    dim3(512),   dim3(128),  0, stream, p, x, qxyz, nidx, W, stats);
    hipLaunchKernelGGL(finalize_kernel, dim3(1),     dim3(128),  0, stream, gamma, beta, stats, out);
    hipLaunchKernelGGL(out_kernel,      dim3(M_PTS), dim3(128),  0, stream, p, x, qxyz, nidx, W, stats, out);
}

// Round 4
// 8233.939 us; speedup vs baseline: 2.1532x; 2.1532x over previous
//
#include <hip/hip_runtime.h>
#include <hip/hip_bf16.h>

#define N_PTS 20000
#define M_PTS 5000
#define NSAMP 16
#define CIN 64
#define COUT 128
#define FDIM 67          // 3 + CIN
#define NPT 40           // ceil(20000/512) points per thread in FPS

typedef unsigned long long u64;

// monotone float->uint mapping (handles negative d from cancellation in knn)
__device__ __forceinline__ unsigned f2ord(float f) {
    unsigned u = __float_as_uint(f);
    return u ^ (((unsigned)((int)u >> 31)) | 0x80000000u);
}

// ---------------------------------------------------------------------------
// K1: furthest point sampling. Single block, 512 threads (8 waves, 2/SIMD).
// Coords+dists register-resident (160 VGPR; launch_bounds(512,2) caps at 256
// so NO scratch spill — R3's VGPR=64 spill was the 17ms culprit).
// One barrier/iteration via parity-double-buffered leader slots.
// ---------------------------------------------------------------------------
__global__ __launch_bounds__(512, 2) void fps_kernel(
    const float* __restrict__ p,
    float* __restrict__ qxyz,          // [M*3] fp32 sampled coords (ws)
    float* __restrict__ stats,         // zero first 256 floats (BN accumulators)
    float* __restrict__ out)           // f32 output buffer
{
    const int t = threadIdx.x;
    const int wid = t >> 6;
    __shared__ u64 wred[2][8];

    if (t < 256) stats[t] = 0.0f;

    float px[NPT], py[NPT], pz[NPT], dist[NPT];
#pragma unroll
    for (int i = 0; i < NPT; ++i) {
        int idx = t + i * 512;
        bool v = idx < N_PTS;
        px[i]   = v ? p[3 * idx + 0] : 0.0f;
        py[i]   = v ? p[3 * idx + 1] : 0.0f;
        pz[i]   = v ? p[3 * idx + 2] : 0.0f;
        dist[i] = v ? 1e10f : -1.0f;           // masked points never win
    }

    float lx = p[0], ly = p[1], lz = p[2];
    if (t == 0) {
        qxyz[0] = lx; qxyz[1] = ly; qxyz[2] = lz;
        out[0] = lx; out[1] = ly; out[2] = lz;
        out[M_PTS * 3 + M_PTS * COUT] = (float)M_PTS;   // n_o = 5000
    }

    for (int it = 1; it < M_PTS; ++it) {
        // --- update min-dists and track per-thread argmax (slot only) ---
        float lm = -1.0f;
        int slot = 0;
#pragma unroll
        for (int i = 0; i < NPT; ++i) {
            float dx = px[i] - lx, dy = py[i] - ly, dz = pz[i] - lz;
            float d = fmaf(dx, dx, fmaf(dy, dy, dz * dz));
            float nd = fminf(dist[i], d);
            dist[i] = nd;
            if (nd > lm) { lm = nd; slot = i; }
        }
        // --- wave max (value-only) then ballot to recover the index ---
        float wv = lm;
#pragma unroll
        for (int off = 32; off; off >>= 1)
            wv = fmaxf(wv, __shfl_xor(wv, off, 64));
        u64 mask = __ballot(lm == wv);
        int lane = __ffsll((unsigned long long)mask) - 1;
        int widx = __shfl(t + slot * 512, lane, 64);   // wave winner's global idx

        if ((t & 63) == 0)
            wred[it & 1][wid] = ((u64)__float_as_uint(wv) << 32) | (unsigned)widx;
        __syncthreads();

        // --- all threads redundantly reduce the 8 wave keys ---
        u64 best = wred[it & 1][0];
#pragma unroll
        for (int j = 1; j < 8; ++j) {
            u64 o = wred[it & 1][j];
            best = (o > best) ? o : best;
        }
        int w = (int)(unsigned)(best & 0xFFFFFFFFu);
        // broadcast coord fetch: same address in all lanes -> one L2 transaction
        lx = p[3 * w]; ly = p[3 * w + 1]; lz = p[3 * w + 2];
        if (t == 0) {
            qxyz[3 * it] = lx; qxyz[3 * it + 1] = ly; qxyz[3 * it + 2] = lz;
            out[3 * it] = lx; out[3 * it + 1] = ly; out[3 * it + 2] = lz;
        }
    }
}

// ---------------------------------------------------------------------------
// K2: kNN (k=16) per query. One block (256 threads) per query.
// launch_bounds(256,4) -> 128 VGPR cap so kv[16] stays in registers
// (R3's VGPR=40 spilled it to scratch).
// ---------------------------------------------------------------------------
__global__ __launch_bounds__(256, 4) void knn_kernel(
    const float* __restrict__ p,
    const float* __restrict__ qxyz,
    int* __restrict__ nidx)
{
    const int m = blockIdx.x;
    const int t = threadIdx.x;
    __shared__ u64 red[4];

    const float qx = qxyz[3 * m], qy = qxyz[3 * m + 1], qz = qxyz[3 * m + 2];
    const float qq = __fadd_rn(__fadd_rn(__fmul_rn(qx, qx), __fmul_rn(qy, qy)),
                               __fmul_rn(qz, qz));

    u64 kv[NSAMP];
#pragma unroll
    for (int j = 0; j < NSAMP; ++j) kv[j] = ~0ULL;
    u64 curmax = ~0ULL;
    int cslot = 0;

#pragma unroll 2
    for (int i = 0; i < 79; ++i) {
        int n = t + i * 256;
        if (n < N_PTS) {
            float px = p[3 * n], py = p[3 * n + 1], pz = p[3 * n + 2];
            float pp = __fadd_rn(__fadd_rn(__fmul_rn(px, px), __fmul_rn(py, py)),
                                 __fmul_rn(pz, pz));
            float qp = __fadd_rn(__fadd_rn(__fmul_rn(qx, px), __fmul_rn(qy, py)),
                                 __fmul_rn(qz, pz));
            float d = __fadd_rn(__fsub_rn(qq, __fmul_rn(2.0f, qp)), pp);
            u64 key = ((u64)f2ord(d) << 32) | (unsigned)n;
            if (key < curmax) {
#pragma unroll
                for (int j = 0; j < NSAMP; ++j) if (j == cslot) kv[j] = key;
                curmax = 0;
#pragma unroll
                for (int j = 0; j < NSAMP; ++j)
                    if (kv[j] > curmax) { curmax = kv[j]; cslot = j; }
            }
        }
    }

    // merge 256x16 -> global top-16 (16 rounds of block argmin; keys unique)
    for (int r = 0; r < NSAMP; ++r) {
        u64 my = kv[0];
#pragma unroll
        for (int j = 1; j < NSAMP; ++j) my = (kv[j] < my) ? kv[j] : my;
        u64 k = my;
#pragma unroll
        for (int off = 32; off; off >>= 1) {
            u64 o = __shfl_xor(k, off, 64);
            k = (o < k) ? o : k;
        }
        if ((t & 63) == 0) red[t >> 6] = k;
        __syncthreads();
        u64 win = red[0];
        win = (red[1] < win) ? red[1] : win;
        win = (red[2] < win) ? red[2] : win;
        win = (red[3] < win) ? red[3] : win;
        if (my == win) {
#pragma unroll
            for (int j = 0; j < NSAMP; ++j) if (kv[j] == win) kv[j] = ~0ULL;
        }
        if (t == 0) nidx[m * NSAMP + r] = (int)(unsigned)(win & 0xFFFFFFFFu);
        __syncthreads();
    }
}

// ---------------------------------------------------------------------------
// K3: BN batch statistics. Row (m,j) -> feat[67] -> h[c]; accumulate sum/sumsq.
// ---------------------------------------------------------------------------
__global__ __launch_bounds__(128) void stats_kernel(
    const float* __restrict__ p,
    const float* __restrict__ x,
    const float* __restrict__ qxyz,
    const int* __restrict__ nidx,
    const float* __restrict__ W,
    float* __restrict__ stats)
{
    __shared__ float Wl[FDIM][COUT];
    __shared__ float feat[FDIM];
    const int t = threadIdx.x;

    for (int k = 0; k < FDIM; ++k) Wl[k][t] = W[k * COUT + t];

    float s = 0.0f, sq = 0.0f;
    for (int r = blockIdx.x; r < M_PTS * NSAMP; r += gridDim.x) {
        int m = r >> 4, j = r & 15;
        int n = nidx[m * NSAMP + j];
        n = max(0, min(n, N_PTS - 1));       // fault guard (no-op when nidx valid)
        __syncthreads();
        if (t < 3)         feat[t] = p[3 * n + t] - qxyz[3 * m + t];
        else if (t < FDIM) feat[t] = x[n * CIN + (t - 3)];
        __syncthreads();
        float h = 0.0f;
#pragma unroll
        for (int k = 0; k < FDIM; ++k) h = fmaf(feat[k], Wl[k][t], h);
        s += h;
        sq = fmaf(h, h, sq);
    }
    atomicAdd(&stats[t], s);
    atomicAdd(&stats[128 + t], sq);
}

// ---------------------------------------------------------------------------
// K4: finalize BN -> scale/shift (+ redundant n_o write)
// ---------------------------------------------------------------------------
__global__ __launch_bounds__(128) void finalize_kernel(
    const float* __restrict__ gamma,
    const float* __restrict__ beta,
    float* __restrict__ stats,
    float* __restrict__ out)
{
    const int t = threadIdx.x;
    const float inv = 1.0f / (float)(M_PTS * NSAMP);
    float mean = stats[t] * inv;
    float var = stats[128 + t] * inv - mean * mean;
    var = fmaxf(var, 0.0f);
    float sc = gamma[t] * rsqrtf(var + 1e-5f);
    stats[256 + t] = sc;
    stats[384 + t] = beta[t] - mean * sc;
    if (t == 0) out[M_PTS * 3 + M_PTS * COUT] = (float)M_PTS;  // n_o (redundant)
}

// ---------------------------------------------------------------------------
// K5: recompute h, affine + ReLU + max over k, write x_out (f32)
// ---------------------------------------------------------------------------
__global__ __launch_bounds__(128) void out_kernel(
    const float* __restrict__ p,
    const float* __restrict__ x,
    const float* __restrict__ qxyz,
    const int* __restrict__ nidx,
    const float* __restrict__ W,
    const float* __restrict__ stats,
    float* __restrict__ out)
{
    __shared__ float Wl[FDIM][COUT];
    __shared__ float feat[NSAMP][FDIM];
    const int m = blockIdx.x;
    const int t = threadIdx.x;

    for (int k = 0; k < FDIM; ++k) Wl[k][t] = W[k * COUT + t];

    for (int e = t; e < NSAMP * FDIM; e += 128) {
        int j = e / FDIM, k = e - j * FDIM;
        int n = nidx[m * NSAMP + j];
        n = max(0, min(n, N_PTS - 1));       // fault guard
        feat[j][k] = (k < 3) ? (p[3 * n + k] - qxyz[3 * m + k])
                             : x[n * CIN + (k - 3)];
    }
    __syncthreads();

    const float sc = stats[256 + t], sh = stats[384 + t];
    float mx = 0.0f;                       // relu(h) >= 0, so max >= 0
#pragma unroll
    for (int j = 0; j < NSAMP; ++j) {
        float h = 0.0f;
#pragma unroll
        for (int k = 0; k < FDIM; ++k) h = fmaf(feat[j][k], Wl[k][t], h);
        float y = fmaf(h, sc, sh);
        mx = fmaxf(mx, y);
    }
    out[M_PTS * 3 + m * COUT + t] = mx;
}

// ---------------------------------------------------------------------------
extern "C" void kernel_launch(void* const* d_in, const int* in_sizes, int n_in,
                              void* d_out, int out_size, void* d_ws, size_t ws_size,
                              hipStream_t stream)
{
    (void)in_sizes; (void)n_in; (void)out_size; (void)ws_size;
    const float* p     = (const float*)d_in[0];
    const float* x     = (const float*)d_in[1];
    const float* W     = (const float*)d_in[3];
    const float* gamma = (const float*)d_in[4];
    const float* beta  = (const float*)d_in[5];
    float* out = (float*)d_out;          // reference outputs are float32

    float* qxyz  = (float*)d_ws;                       // 15000 f32
    int*   nidx  = (int*)((char*)d_ws + 60000);        // 80000 i32
    float* stats = (float*)((char*)d_ws + 380000);     // 512 f32

    hipLaunchKernelGGL(fps_kernel,      dim3(1),     dim3(512),  0, stream, p, qxyz, stats, out);
    hipLaunchKernelGGL(knn_kernel,      dim3(M_PTS), dim3(256),  0, stream, p, qxyz, nidx);
    hipLaunchKernelGGL(stats_kernel,    dim3(512),   dim3(128),  0, stream, p, x, qxyz, nidx, W, stats);
    hipLaunchKernelGGL(finalize_kernel, dim3(1),     dim3(128),  0, stream, gamma, beta, stats, out);
    hipLaunchKernelGGL(out_kernel,      dim3(M_PTS), dim3(128),  0, stream, p, x, qxyz, nidx, W, stats, out);
}